// Round 2
// baseline (415.855 us; speedup 1.0000x reference)
//
#include <hip/hip_runtime.h>
#include <math.h>

// Problem constants (B,N,D)=(8,2048,256), S=128, H=512, E=2H+S=1152
#define BB 8
#define NN 2048
#define DD 256
#define SS 128
#define HH 512
#define EE 1152

typedef short bf16x8 __attribute__((ext_vector_type(8)));
typedef float f32x4 __attribute__((ext_vector_type(4)));

__device__ __forceinline__ short f2bf(float f) {
    union { float f; unsigned u; } a; a.f = f;
    unsigned r = a.u + 0x7FFFu + ((a.u >> 16) & 1u);  // RNE
    return (short)(r >> 16);
}
__device__ __forceinline__ float bf2f(short s) {
    union { unsigned u; float f; } a; a.u = ((unsigned)(unsigned short)s) << 16;
    return a.f;
}

// ---------------- K1: RMS norm, x fp32 -> xn bf16 --------------------------
// 4 waves/block, one row (D=256) per wave, float4 loads + shuffle reduce.
__global__ __launch_bounds__(256) void k_rmsnorm(
        const float* __restrict__ x, const float* __restrict__ gp,
        short* __restrict__ xn) {
    int wave = threadIdx.x >> 6, lane = threadIdx.x & 63;
    long row = (long)blockIdx.x * 4 + wave;
    float4 xv = ((const float4*)(x + row * DD))[lane];
    float ss = xv.x*xv.x + xv.y*xv.y + xv.z*xv.z + xv.w*xv.w;
    #pragma unroll
    for (int off = 32; off > 0; off >>= 1) ss += __shfl_down(ss, off);
    ss = __shfl(ss, 0);
    float norm = sqrtf(ss) * 0.0625f;              // ||x|| / sqrt(256)
    float scale = gp[0] / fmaxf(norm, 1e-5f);
    short4 o;
    o.x = f2bf(xv.x * scale); o.y = f2bf(xv.y * scale);
    o.z = f2bf(xv.z * scale); o.w = f2bf(xv.w * scale);
    ((short4*)(xn + row * DD))[lane] = o;
}

// ---------------- K2: weight prep (transpose + bf16 cast) ------------------
// Wuv (D x E) -> Wuv_t (E x D) bf16 ; Wo (H x D) -> Wo_t (D x H) bf16
__global__ void k_prep(const float* __restrict__ Wuv, const float* __restrict__ Wo,
                       short* __restrict__ Wuv_t, short* __restrict__ Wo_t) {
    int idx = blockIdx.x * 256 + threadIdx.x;
    if (idx < DD * EE) {
        int d = idx / EE, e = idx % EE;
        Wuv_t[e * DD + d] = f2bf(Wuv[idx]);
    }
    int i2 = idx - DD * EE;
    if (i2 >= 0 && i2 < HH * DD) {
        int h = i2 / DD, d = i2 % DD;
        Wo_t[d * HH + h] = f2bf(Wo[i2]);
    }
}

// ---------------- K3: GEMM1 + silu + split epilogue ------------------------
// (16384 x 256) @ (256 x 1152), 64x64 tile/block, 4 waves, 16x16x32 MFMA.
__global__ __launch_bounds__(256) void k_gemm1(
        const short* __restrict__ xn, const short* __restrict__ Wuv_t,
        const float* __restrict__ b_uv,
        const float* __restrict__ gamma, const float* __restrict__ beta,
        short* __restrict__ u, short* __restrict__ v,
        short* __restrict__ q, short* __restrict__ k) {
    __shared__ short As[64][72];
    __shared__ short Bs[64][72];
    int m0 = blockIdx.x * 64, n0 = blockIdx.y * 64;
    int t = threadIdx.x, w = t >> 6, lane = t & 63;
    int wr = w & 1, wc = w >> 1, l16 = lane & 15, quad = lane >> 4;
    int srow = t >> 3, sch = (t & 7) * 8;
    f32x4 acc[2][2] = {};
    for (int k0 = 0; k0 < DD; k0 += 64) {
        __syncthreads();
        *(bf16x8*)&As[srow][sch]    = *(const bf16x8*)&xn[(long)(m0+srow)*DD + k0 + sch];
        *(bf16x8*)&As[srow+32][sch] = *(const bf16x8*)&xn[(long)(m0+srow+32)*DD + k0 + sch];
        *(bf16x8*)&Bs[srow][sch]    = *(const bf16x8*)&Wuv_t[(long)(n0+srow)*DD + k0 + sch];
        *(bf16x8*)&Bs[srow+32][sch] = *(const bf16x8*)&Wuv_t[(long)(n0+srow+32)*DD + k0 + sch];
        __syncthreads();
        #pragma unroll
        for (int kk = 0; kk < 2; kk++) {
            bf16x8 a0 = *(const bf16x8*)&As[wr*32 +      l16][kk*32 + quad*8];
            bf16x8 a1 = *(const bf16x8*)&As[wr*32 + 16 + l16][kk*32 + quad*8];
            bf16x8 b0 = *(const bf16x8*)&Bs[wc*32 +      l16][kk*32 + quad*8];
            bf16x8 b1 = *(const bf16x8*)&Bs[wc*32 + 16 + l16][kk*32 + quad*8];
            acc[0][0] = __builtin_amdgcn_mfma_f32_16x16x32_bf16(a0, b0, acc[0][0], 0,0,0);
            acc[0][1] = __builtin_amdgcn_mfma_f32_16x16x32_bf16(a0, b1, acc[0][1], 0,0,0);
            acc[1][0] = __builtin_amdgcn_mfma_f32_16x16x32_bf16(a1, b0, acc[1][0], 0,0,0);
            acc[1][1] = __builtin_amdgcn_mfma_f32_16x16x32_bf16(a1, b1, acc[1][1], 0,0,0);
        }
    }
    #pragma unroll
    for (int mt = 0; mt < 2; mt++)
    #pragma unroll
    for (int nt = 0; nt < 2; nt++)
    #pragma unroll
    for (int r = 0; r < 4; r++) {
        int gm = m0 + wr*32 + mt*16 + quad*4 + r;     // C/D: row=(lane>>4)*4+reg
        int ge = n0 + wc*32 + nt*16 + l16;            //      col=lane&15
        float val = acc[mt][nt][r] + b_uv[ge];
        val = val / (1.0f + __expf(-val));            // silu
        if (ge < HH) {
            u[(long)gm*HH + ge] = f2bf(val);
        } else if (ge < 2*HH) {
            v[(long)gm*HH + (ge - HH)] = f2bf(val);
        } else {
            int si = ge - 2*HH;
            q[(long)gm*SS + si] = f2bf(val * gamma[si]      + beta[si]);
            k[(long)gm*SS + si] = f2bf(val * gamma[SS + si] + beta[SS + si]);
        }
    }
}

// ---------------- K4: transpose v -> v_t per batch -------------------------
__global__ void k_transpose_v(const short* __restrict__ v, short* __restrict__ v_t) {
    __shared__ short tile[32][33];
    int n0 = blockIdx.x * 32, h0 = blockIdx.y * 32, b = blockIdx.z;
    int t = threadIdx.x;
    const short* vb = v + (long)b * NN * HH;
    short* vtb = v_t + (long)b * HH * NN;
    #pragma unroll
    for (int i = 0; i < 4; i++) {
        int idx = t + i * 256, r = idx >> 5, c = idx & 31;
        tile[r][c] = vb[(long)(n0 + r) * HH + h0 + c];
    }
    __syncthreads();
    #pragma unroll
    for (int i = 0; i < 4; i++) {
        int idx = t + i * 256, r = idx >> 5, c = idx & 31;
        vtb[(long)(h0 + r) * NN + n0 + c] = tile[c][r];
    }
}

// ---------------- K5: fused relu^2 attention + u-gate (v2) -----------------
// Block = (batch, 64 q-rows), 8 waves (512 thr), grid 256 = 1 block/CU.
// Wave w: q-tile qt=w>>1 (16 rows), h-half hh=w&1 (256 cols = 16 col-tiles).
// S^T = K·Q^T: A = k-frags from GLOBAL (L2), B = q-frags in REGISTERS
// (loop-invariant). P round-trips through a tiny double-buffered LDS tile
// (only 12 KB traffic/iter vs 142 KB in v1). v-frags straight from global:
// each wave reads distinct v rows, so LDS staging was pure overhead.
// blockIdx&7 = batch -> batch's k/v (~2.5MB) pinned to one XCD L2.
__global__ __launch_bounds__(512, 2) void k_attn(
        const short* __restrict__ q, const short* __restrict__ k,
        const short* __restrict__ v_t, const short* __restrict__ u,
        short* __restrict__ gated) {
    __shared__ short Ps[2][64][48];   // stride 48 shorts: 16B-aligned rows, b128 reads at bank floor
    int b = blockIdx.x & 7;
    int i0 = (blockIdx.x >> 3) * 64;
    int t = threadIdx.x, w = t >> 6, lane = t & 63;
    int l16 = lane & 15, quad = lane >> 4;
    int qt = w >> 1, hh = w & 1;
    const short* qb  = q   + ((long)b * NN + i0) * SS;
    const short* kb  = k   + (long)b * NN * SS;
    const short* vtb = v_t + ((long)b * HH + hh * 256) * NN;
    const float RS = 0.08838834764831845f;  // 1/sqrt(128)

    // Hoist q B-frags: B[n=q-local=l16][k=s=quad*8+j], one per s-chunk.
    bf16x8 qf[4];
    #pragma unroll
    for (int kc = 0; kc < 4; kc++)
        qf[kc] = *(const bf16x8*)&qb[(long)(qt*16 + l16)*SS + kc*32 + quad*8];

    f32x4 acc[16] = {};
    #pragma unroll 2
    for (int m0 = 0; m0 < NN; m0 += 32) {
        int buf = (m0 >> 5) & 1;
        // k A-frags for S^T tile (m-tile = hh): A[m-local=l16][k=s]
        bf16x8 kf[4];
        #pragma unroll
        for (int kc = 0; kc < 4; kc++)
            kf[kc] = *(const bf16x8*)&kb[(long)(m0 + hh*16 + l16)*SS + kc*32 + quad*8];
        // v B-frags, first half (in flight during QK): B[n=h-local=l16][k=m]
        bf16x8 vfa[8];
        #pragma unroll
        for (int j = 0; j < 8; j++)
            vfa[j] = *(const bf16x8*)&vtb[(long)(j*16 + l16)*NN + m0 + quad*8];
        // S^T tile: rows=m-local (quad*4+r), cols=q-local (l16)
        f32x4 sc = {};
        #pragma unroll
        for (int kc = 0; kc < 4; kc++)
            sc = __builtin_amdgcn_mfma_f32_16x16x32_bf16(kf[kc], qf[kc], sc, 0,0,0);
        short4 pw;
        {
            float s0 = fmaxf(sc[0]*RS, 0.f), s1 = fmaxf(sc[1]*RS, 0.f);
            float s2 = fmaxf(sc[2]*RS, 0.f), s3 = fmaxf(sc[3]*RS, 0.f);
            pw.x = f2bf(s0*s0); pw.y = f2bf(s1*s1);
            pw.z = f2bf(s2*s2); pw.w = f2bf(s3*s3);
        }
        // P^T stored as Ps[q 0..63][m 0..31]
        *(short4*)&Ps[buf][qt*16 + l16][hh*16 + quad*4] = pw;
        __syncthreads();
        // PV: A = P-frag A[q=l16][m=quad*8+j] (covers full m-tile of 32)
        bf16x8 ap = *(const bf16x8*)&Ps[buf][qt*16 + l16][quad*8];
        #pragma unroll
        for (int j = 0; j < 8; j++)
            acc[j] = __builtin_amdgcn_mfma_f32_16x16x32_bf16(ap, vfa[j], acc[j], 0,0,0);
        bf16x8 vfb[8];
        #pragma unroll
        for (int j = 0; j < 8; j++)
            vfb[j] = *(const bf16x8*)&vtb[(long)((8+j)*16 + l16)*NN + m0 + quad*8];
        #pragma unroll
        for (int j = 0; j < 8; j++)
            acc[8+j] = __builtin_amdgcn_mfma_f32_16x16x32_bf16(ap, vfb[j], acc[8+j], 0,0,0);
    }

    // epilogue: u-gate.  acc C-layout: row q = quad*4+r, col h = l16
    long rowbase = (long)b * NN + i0 + qt*16;
    #pragma unroll
    for (int j = 0; j < 16; j++) {
        int gh = hh*256 + j*16 + l16;
        #pragma unroll
        for (int r = 0; r < 4; r++) {
            long grow = rowbase + quad*4 + r;
            float uval = bf2f(u[grow * HH + gh]);
            gated[grow * HH + gh] = f2bf(acc[j][r] * uval);
        }
    }
}

// ---------------- K6: GEMM2 + bias -> fp32 out -----------------------------
__global__ __launch_bounds__(256) void k_gemm2(
        const short* __restrict__ gated, const short* __restrict__ Wo_t,
        const float* __restrict__ b_o, float* __restrict__ out) {
    __shared__ short As[64][72];
    __shared__ short Bs[64][72];
    int m0 = blockIdx.x * 64, n0 = blockIdx.y * 64;
    int t = threadIdx.x, w = t >> 6, lane = t & 63;
    int wr = w & 1, wc = w >> 1, l16 = lane & 15, quad = lane >> 4;
    int srow = t >> 3, sch = (t & 7) * 8;
    f32x4 acc[2][2] = {};
    for (int k0 = 0; k0 < HH; k0 += 64) {
        __syncthreads();
        *(bf16x8*)&As[srow][sch]    = *(const bf16x8*)&gated[(long)(m0+srow)*HH + k0 + sch];
        *(bf16x8*)&As[srow+32][sch] = *(const bf16x8*)&gated[(long)(m0+srow+32)*HH + k0 + sch];
        *(bf16x8*)&Bs[srow][sch]    = *(const bf16x8*)&Wo_t[(long)(n0+srow)*HH + k0 + sch];
        *(bf16x8*)&Bs[srow+32][sch] = *(const bf16x8*)&Wo_t[(long)(n0+srow+32)*HH + k0 + sch];
        __syncthreads();
        #pragma unroll
        for (int kk = 0; kk < 2; kk++) {
            bf16x8 a0 = *(const bf16x8*)&As[wr*32 +      l16][kk*32 + quad*8];
            bf16x8 a1 = *(const bf16x8*)&As[wr*32 + 16 + l16][kk*32 + quad*8];
            bf16x8 b0 = *(const bf16x8*)&Bs[wc*32 +      l16][kk*32 + quad*8];
            bf16x8 b1 = *(const bf16x8*)&Bs[wc*32 + 16 + l16][kk*32 + quad*8];
            acc[0][0] = __builtin_amdgcn_mfma_f32_16x16x32_bf16(a0, b0, acc[0][0], 0,0,0);
            acc[0][1] = __builtin_amdgcn_mfma_f32_16x16x32_bf16(a0, b1, acc[0][1], 0,0,0);
            acc[1][0] = __builtin_amdgcn_mfma_f32_16x16x32_bf16(a1, b0, acc[1][0], 0,0,0);
            acc[1][1] = __builtin_amdgcn_mfma_f32_16x16x32_bf16(a1, b1, acc[1][1], 0,0,0);
        }
    }
    #pragma unroll
    for (int mt = 0; mt < 2; mt++)
    #pragma unroll
    for (int nt = 0; nt < 2; nt++)
    #pragma unroll
    for (int r = 0; r < 4; r++) {
        int gm = m0 + wr*32 + mt*16 + quad*4 + r;
        int gd = n0 + wc*32 + nt*16 + l16;
        out[(long)gm*DD + gd] = acc[mt][nt][r] + b_o[gd];
    }
}

extern "C" void kernel_launch(void* const* d_in, const int* in_sizes, int n_in,
                              void* d_out, int out_size, void* d_ws, size_t ws_size,
                              hipStream_t stream) {
    const float* x     = (const float*)d_in[0];
    const float* g     = (const float*)d_in[1];
    const float* Wuv   = (const float*)d_in[2];
    const float* b_uv  = (const float*)d_in[3];
    const float* gamma = (const float*)d_in[4];
    const float* beta  = (const float*)d_in[5];
    const float* Wo    = (const float*)d_in[6];
    const float* b_o   = (const float*)d_in[7];
    float* out = (float*)d_out;

    // workspace layout (bf16/short elements), ~84.7 MB total
    short* ws    = (short*)d_ws;
    short* xn    = ws;                                  // 16384*256
    short* Wuv_t = xn    + (long)16384 * 256;           // 1152*256
    short* Wo_t  = Wuv_t + (long)1152 * 256;            // 256*512
    short* u     = Wo_t  + (long)256 * 512;             // 16384*512
    short* v     = u     + (long)16384 * 512;           // 16384*512
    short* v_t   = v     + (long)16384 * 512;           // 16384*512
    short* qq    = v_t   + (long)16384 * 512;           // 16384*128
    short* kk    = qq    + (long)16384 * 128;           // 16384*128
    short* gated = kk    + (long)16384 * 128;           // 16384*512

    k_rmsnorm<<<4096, 256, 0, stream>>>(x, g, xn);
    k_prep<<<(DD*EE + HH*DD + 255) / 256, 256, 0, stream>>>(Wuv, Wo, Wuv_t, Wo_t);
    k_gemm1<<<dim3(256, 18), 256, 0, stream>>>(xn, Wuv_t, b_uv, gamma, beta, u, v, qq, kk);
    k_transpose_v<<<dim3(64, 16, 8), 256, 0, stream>>>(v, v_t);
    k_attn<<<256, 512, 0, stream>>>(qq, kk, v_t, u, gated);
    k_gemm2<<<dim3(256, 4), 256, 0, stream>>>(gated, Wo_t, b_o, out);
}

// Round 3
// 238.559 us; speedup vs baseline: 1.7432x; 1.7432x over previous
//
#include <hip/hip_runtime.h>
#include <math.h>

// Problem constants (B,N,D)=(8,2048,256), S=128, H=512, E=2H+S=1152
#define BB 8
#define NN 2048
#define DD 256
#define SS 128
#define HH 512
#define EE 1152

typedef short bf16x8 __attribute__((ext_vector_type(8)));
typedef float f32x4 __attribute__((ext_vector_type(4)));

__device__ __forceinline__ short f2bf(float f) {
    union { float f; unsigned u; } a; a.f = f;
    unsigned r = a.u + 0x7FFFu + ((a.u >> 16) & 1u);  // RNE
    return (short)(r >> 16);
}
__device__ __forceinline__ float bf2f(short s) {
    union { unsigned u; float f; } a; a.u = ((unsigned)(unsigned short)s) << 16;
    return a.f;
}

// ---------------- K1: RMS norm, x fp32 -> xn bf16 --------------------------
__global__ __launch_bounds__(256) void k_rmsnorm(
        const float* __restrict__ x, const float* __restrict__ gp,
        short* __restrict__ xn) {
    int wave = threadIdx.x >> 6, lane = threadIdx.x & 63;
    long row = (long)blockIdx.x * 4 + wave;
    float4 xv = ((const float4*)(x + row * DD))[lane];
    float ss = xv.x*xv.x + xv.y*xv.y + xv.z*xv.z + xv.w*xv.w;
    #pragma unroll
    for (int off = 32; off > 0; off >>= 1) ss += __shfl_down(ss, off);
    ss = __shfl(ss, 0);
    float norm = sqrtf(ss) * 0.0625f;              // ||x|| / sqrt(256)
    float scale = gp[0] / fmaxf(norm, 1e-5f);
    short4 o;
    o.x = f2bf(xv.x * scale); o.y = f2bf(xv.y * scale);
    o.z = f2bf(xv.z * scale); o.w = f2bf(xv.w * scale);
    ((short4*)(xn + row * DD))[lane] = o;
}

// ---------------- K2: weight prep (transpose + bf16 cast) ------------------
__global__ void k_prep(const float* __restrict__ Wuv, const float* __restrict__ Wo,
                       short* __restrict__ Wuv_t, short* __restrict__ Wo_t) {
    int idx = blockIdx.x * 256 + threadIdx.x;
    if (idx < DD * EE) {
        int d = idx / EE, e = idx % EE;
        Wuv_t[e * DD + d] = f2bf(Wuv[idx]);
    }
    int i2 = idx - DD * EE;
    if (i2 >= 0 && i2 < HH * DD) {
        int h = i2 / DD, d = i2 % DD;
        Wo_t[d * HH + h] = f2bf(Wo[i2]);
    }
}

// ---------------- K3: GEMM1 + silu + split epilogue ------------------------
__global__ __launch_bounds__(256) void k_gemm1(
        const short* __restrict__ xn, const short* __restrict__ Wuv_t,
        const float* __restrict__ b_uv,
        const float* __restrict__ gamma, const float* __restrict__ beta,
        short* __restrict__ u, short* __restrict__ v,
        short* __restrict__ q, short* __restrict__ k) {
    __shared__ short As[64][72];
    __shared__ short Bs[64][72];
    int m0 = blockIdx.x * 64, n0 = blockIdx.y * 64;
    int t = threadIdx.x, w = t >> 6, lane = t & 63;
    int wr = w & 1, wc = w >> 1, l16 = lane & 15, quad = lane >> 4;
    int srow = t >> 3, sch = (t & 7) * 8;
    f32x4 acc[2][2] = {};
    for (int k0 = 0; k0 < DD; k0 += 64) {
        __syncthreads();
        *(bf16x8*)&As[srow][sch]    = *(const bf16x8*)&xn[(long)(m0+srow)*DD + k0 + sch];
        *(bf16x8*)&As[srow+32][sch] = *(const bf16x8*)&xn[(long)(m0+srow+32)*DD + k0 + sch];
        *(bf16x8*)&Bs[srow][sch]    = *(const bf16x8*)&Wuv_t[(long)(n0+srow)*DD + k0 + sch];
        *(bf16x8*)&Bs[srow+32][sch] = *(const bf16x8*)&Wuv_t[(long)(n0+srow+32)*DD + k0 + sch];
        __syncthreads();
        #pragma unroll
        for (int kk = 0; kk < 2; kk++) {
            bf16x8 a0 = *(const bf16x8*)&As[wr*32 +      l16][kk*32 + quad*8];
            bf16x8 a1 = *(const bf16x8*)&As[wr*32 + 16 + l16][kk*32 + quad*8];
            bf16x8 b0 = *(const bf16x8*)&Bs[wc*32 +      l16][kk*32 + quad*8];
            bf16x8 b1 = *(const bf16x8*)&Bs[wc*32 + 16 + l16][kk*32 + quad*8];
            acc[0][0] = __builtin_amdgcn_mfma_f32_16x16x32_bf16(a0, b0, acc[0][0], 0,0,0);
            acc[0][1] = __builtin_amdgcn_mfma_f32_16x16x32_bf16(a0, b1, acc[0][1], 0,0,0);
            acc[1][0] = __builtin_amdgcn_mfma_f32_16x16x32_bf16(a1, b0, acc[1][0], 0,0,0);
            acc[1][1] = __builtin_amdgcn_mfma_f32_16x16x32_bf16(a1, b1, acc[1][1], 0,0,0);
        }
    }
    #pragma unroll
    for (int mt = 0; mt < 2; mt++)
    #pragma unroll
    for (int nt = 0; nt < 2; nt++)
    #pragma unroll
    for (int r = 0; r < 4; r++) {
        int gm = m0 + wr*32 + mt*16 + quad*4 + r;     // C/D: row=(lane>>4)*4+reg
        int ge = n0 + wc*32 + nt*16 + l16;            //      col=lane&15
        float val = acc[mt][nt][r] + b_uv[ge];
        val = val / (1.0f + __expf(-val));            // silu
        if (ge < HH) {
            u[(long)gm*HH + ge] = f2bf(val);
        } else if (ge < 2*HH) {
            v[(long)gm*HH + (ge - HH)] = f2bf(val);
        } else {
            int si = ge - 2*HH;
            q[(long)gm*SS + si] = f2bf(val * gamma[si]      + beta[si]);
            k[(long)gm*SS + si] = f2bf(val * gamma[SS + si] + beta[SS + si]);
        }
    }
}

// ---------------- K4: transpose v -> v_t per batch -------------------------
__global__ void k_transpose_v(const short* __restrict__ v, short* __restrict__ v_t) {
    __shared__ short tile[32][33];
    int n0 = blockIdx.x * 32, h0 = blockIdx.y * 32, b = blockIdx.z;
    int t = threadIdx.x;
    const short* vb = v + (long)b * NN * HH;
    short* vtb = v_t + (long)b * HH * NN;
    #pragma unroll
    for (int i = 0; i < 4; i++) {
        int idx = t + i * 256, r = idx >> 5, c = idx & 31;
        tile[r][c] = vb[(long)(n0 + r) * HH + h0 + c];
    }
    __syncthreads();
    #pragma unroll
    for (int i = 0; i < 4; i++) {
        int idx = t + i * 256, r = idx >> 5, c = idx & 31;
        vtb[(long)(h0 + r) * NN + n0 + c] = tile[c][r];
    }
}

// ---------------- K5: fused relu^2 attention + u-gate (v3) -----------------
// Block = (batch, 64 q-rows), 8 waves (512 thr), grid 256 = 1 block/CU.
// v2 post-mortem: global per-wave fragment loads were 4x redundant and
// scatter-heavy -> L2-bound at 296us. v3 rule: every shared operand staged
// through LDS exactly ONCE per block; register reuse keeps LDS reads at
// 96 b128/iter (vs v1's ~142KB for half the q-rows).
//   QK: wave (qt=w>>1, mt=w&1) computes S^T 16x16; q-frags hoisted in regs.
//   PV: wave owns h-slice of 64 cols; v read 1x; af/vf frags each reused 4x.
//   Global k/v for iter+1 prefetched into VGPRs at iter top, written to LDS
//   after PV (single-buffered LDS, 3 uniform barriers/iter, 54.8KB).
__global__ __launch_bounds__(512, 2) void k_attn(
        const short* __restrict__ q, const short* __restrict__ k,
        const short* __restrict__ v_t, const short* __restrict__ u,
        short* __restrict__ gated) {
    __shared__ short ks[32][136];   // k-tile: 32 m-rows x 128 s (+8 pad)
    __shared__ short vts[512][40];  // v-tile: 512 h-rows x 32 m (+8 pad)
    __shared__ short Ps[64][40];    // P: 64 q-rows x 32 m (+8 pad)
    int b = blockIdx.x & 7;                  // batch -> XCD pin
    int i0 = (blockIdx.x >> 3) * 64;
    int t = threadIdx.x, w = t >> 6, lane = t & 63;
    int l16 = lane & 15, quad = lane >> 4;
    int qt = w >> 1, mt = w & 1;             // QK tile assignment
    const short* qb  = q   + ((long)b * NN + i0) * SS;
    const short* kb  = k   + (long)b * NN * SS;
    const short* vtb = v_t + (long)b * HH * NN;
    const float RS = 0.08838834764831845f;   // 1/sqrt(128)

    // staging index map (same for global load and LDS write)
    int krow = t >> 4, kch = (t & 15) * 8;        // k: 32 rows x 256B
    int vrow = t >> 2, vch = (t & 3) * 8;         // v: 4 rounds of 128 rows x 64B

    // hoist q B-frags for this wave's q-tile: B[k=s][n=q], n=l16
    bf16x8 qf[4];
    #pragma unroll
    for (int kc = 0; kc < 4; kc++)
        qf[kc] = *(const bf16x8*)&qb[(long)(qt*16 + l16)*SS + kc*32 + quad*8];

    // stage m0 = 0
    *(bf16x8*)&ks[krow][kch] = *(const bf16x8*)&kb[(long)krow*SS + kch];
    #pragma unroll
    for (int i = 0; i < 4; i++)
        *(bf16x8*)&vts[vrow + i*128][vch] =
            *(const bf16x8*)&vtb[(long)(vrow + i*128)*NN + vch];
    __syncthreads();

    f32x4 acc[16] = {};
    for (int m0 = 0; m0 < NN; m0 += 32) {
        bool last = (m0 + 32 >= NN);
        // prefetch next k/v tile into VGPRs (lands during QK+PV)
        bf16x8 kpre; bf16x8 vpre[4];
        if (!last) {
            kpre = *(const bf16x8*)&kb[(long)(m0 + 32 + krow)*SS + kch];
            #pragma unroll
            for (int i = 0; i < 4; i++)
                vpre[i] = *(const bf16x8*)&vtb[(long)(vrow + i*128)*NN + m0 + 32 + vch];
        }
        // QK: S^T tile (16m x 16q), A = k-frags from LDS, B = q-frags in regs
        f32x4 sc = {};
        #pragma unroll
        for (int kc = 0; kc < 4; kc++) {
            bf16x8 kf = *(const bf16x8*)&ks[mt*16 + l16][kc*32 + quad*8];
            sc = __builtin_amdgcn_mfma_f32_16x16x32_bf16(kf, qf[kc], sc, 0,0,0);
        }
        short4 pw;
        {
            float s0 = fmaxf(sc[0]*RS, 0.f), s1 = fmaxf(sc[1]*RS, 0.f);
            float s2 = fmaxf(sc[2]*RS, 0.f), s3 = fmaxf(sc[3]*RS, 0.f);
            pw.x = f2bf(s0*s0); pw.y = f2bf(s1*s1);
            pw.z = f2bf(s2*s2); pw.w = f2bf(s3*s3);
        }
        // C-layout: row m = quad*4+r, col q = l16 -> store P[q][m]
        *(short4*)&Ps[qt*16 + l16][mt*16 + quad*4] = pw;
        __syncthreads();                       // A: P complete
        // PV: A-frags (one per q-tile, reused over 4 h-tiles), B = v frags
        bf16x8 af[4];
        #pragma unroll
        for (int qq2 = 0; qq2 < 4; qq2++)
            af[qq2] = *(const bf16x8*)&Ps[qq2*16 + l16][quad*8];
        #pragma unroll
        for (int jj = 0; jj < 4; jj++) {
            bf16x8 vf = *(const bf16x8*)&vts[(w*4 + jj)*16 + l16][quad*8];
            #pragma unroll
            for (int qq2 = 0; qq2 < 4; qq2++)
                acc[qq2*4 + jj] = __builtin_amdgcn_mfma_f32_16x16x32_bf16(
                    af[qq2], vf, acc[qq2*4 + jj], 0,0,0);
        }
        if (!last) {
            __syncthreads();                   // C: vts/ks reads done
            *(bf16x8*)&ks[krow][kch] = kpre;
            #pragma unroll
            for (int i = 0; i < 4; i++)
                *(bf16x8*)&vts[vrow + i*128][vch] = vpre[i];
            __syncthreads();                   // B: staging visible
        }
    }

    // epilogue: u-gate. acc C-layout: row q = quad*4+r, col h = l16
    long rowbase = (long)b * NN + i0;
    #pragma unroll
    for (int qq2 = 0; qq2 < 4; qq2++)
    #pragma unroll
    for (int jj = 0; jj < 4; jj++) {
        int gh = (w*4 + jj)*16 + l16;
        #pragma unroll
        for (int r = 0; r < 4; r++) {
            long grow = rowbase + qq2*16 + quad*4 + r;
            float uval = bf2f(u[grow * HH + gh]);
            gated[grow * HH + gh] = f2bf(acc[qq2*4 + jj][r] * uval);
        }
    }
}

// ---------------- K6: GEMM2 + bias -> fp32 out -----------------------------
__global__ __launch_bounds__(256) void k_gemm2(
        const short* __restrict__ gated, const short* __restrict__ Wo_t,
        const float* __restrict__ b_o, float* __restrict__ out) {
    __shared__ short As[64][72];
    __shared__ short Bs[64][72];
    int m0 = blockIdx.x * 64, n0 = blockIdx.y * 64;
    int t = threadIdx.x, w = t >> 6, lane = t & 63;
    int wr = w & 1, wc = w >> 1, l16 = lane & 15, quad = lane >> 4;
    int srow = t >> 3, sch = (t & 7) * 8;
    f32x4 acc[2][2] = {};
    for (int k0 = 0; k0 < HH; k0 += 64) {
        __syncthreads();
        *(bf16x8*)&As[srow][sch]    = *(const bf16x8*)&gated[(long)(m0+srow)*HH + k0 + sch];
        *(bf16x8*)&As[srow+32][sch] = *(const bf16x8*)&gated[(long)(m0+srow+32)*HH + k0 + sch];
        *(bf16x8*)&Bs[srow][sch]    = *(const bf16x8*)&Wo_t[(long)(n0+srow)*HH + k0 + sch];
        *(bf16x8*)&Bs[srow+32][sch] = *(const bf16x8*)&Wo_t[(long)(n0+srow+32)*HH + k0 + sch];
        __syncthreads();
        #pragma unroll
        for (int kk = 0; kk < 2; kk++) {
            bf16x8 a0 = *(const bf16x8*)&As[wr*32 +      l16][kk*32 + quad*8];
            bf16x8 a1 = *(const bf16x8*)&As[wr*32 + 16 + l16][kk*32 + quad*8];
            bf16x8 b0 = *(const bf16x8*)&Bs[wc*32 +      l16][kk*32 + quad*8];
            bf16x8 b1 = *(const bf16x8*)&Bs[wc*32 + 16 + l16][kk*32 + quad*8];
            acc[0][0] = __builtin_amdgcn_mfma_f32_16x16x32_bf16(a0, b0, acc[0][0], 0,0,0);
            acc[0][1] = __builtin_amdgcn_mfma_f32_16x16x32_bf16(a0, b1, acc[0][1], 0,0,0);
            acc[1][0] = __builtin_amdgcn_mfma_f32_16x16x32_bf16(a1, b0, acc[1][0], 0,0,0);
            acc[1][1] = __builtin_amdgcn_mfma_f32_16x16x32_bf16(a1, b1, acc[1][1], 0,0,0);
        }
    }
    #pragma unroll
    for (int mt = 0; mt < 2; mt++)
    #pragma unroll
    for (int nt = 0; nt < 2; nt++)
    #pragma unroll
    for (int r = 0; r < 4; r++) {
        int gm = m0 + wr*32 + mt*16 + quad*4 + r;
        int gd = n0 + wc*32 + nt*16 + l16;
        out[(long)gm*DD + gd] = acc[mt][nt][r] + b_o[gd];
    }
}

extern "C" void kernel_launch(void* const* d_in, const int* in_sizes, int n_in,
                              void* d_out, int out_size, void* d_ws, size_t ws_size,
                              hipStream_t stream) {
    const float* x     = (const float*)d_in[0];
    const float* g     = (const float*)d_in[1];
    const float* Wuv   = (const float*)d_in[2];
    const float* b_uv  = (const float*)d_in[3];
    const float* gamma = (const float*)d_in[4];
    const float* beta  = (const float*)d_in[5];
    const float* Wo    = (const float*)d_in[6];
    const float* b_o   = (const float*)d_in[7];
    float* out = (float*)d_out;

    short* ws    = (short*)d_ws;
    short* xn    = ws;                                  // 16384*256
    short* Wuv_t = xn    + (long)16384 * 256;           // 1152*256
    short* Wo_t  = Wuv_t + (long)1152 * 256;            // 256*512
    short* u     = Wo_t  + (long)256 * 512;             // 16384*512
    short* v     = u     + (long)16384 * 512;           // 16384*512
    short* v_t   = v     + (long)16384 * 512;           // 16384*512
    short* qq    = v_t   + (long)16384 * 512;           // 16384*128
    short* kk    = qq    + (long)16384 * 128;           // 16384*128
    short* gated = kk    + (long)16384 * 128;           // 16384*512

    k_rmsnorm<<<4096, 256, 0, stream>>>(x, g, xn);
    k_prep<<<(DD*EE + HH*DD + 255) / 256, 256, 0, stream>>>(Wuv, Wo, Wuv_t, Wo_t);
    k_gemm1<<<dim3(256, 18), 256, 0, stream>>>(xn, Wuv_t, b_uv, gamma, beta, u, v, qq, kk);
    k_transpose_v<<<dim3(64, 16, 8), 256, 0, stream>>>(v, v_t);
    k_attn<<<256, 512, 0, stream>>>(qq, kk, v_t, u, gated);
    k_gemm2<<<dim3(256, 4), 256, 0, stream>>>(gated, Wo_t, b_o, out);
}

// Round 4
// 174.057 us; speedup vs baseline: 2.3892x; 1.3706x over previous
//
#include <hip/hip_runtime.h>
#include <math.h>

// Problem constants (B,N,D)=(8,2048,256), S=128, H=512, E=2H+S=1152
#define BB 8
#define NN 2048
#define DD 256
#define SS 128
#define HH 512
#define EE 1152

typedef short bf16x8 __attribute__((ext_vector_type(8)));
typedef float f32x4 __attribute__((ext_vector_type(4)));

__device__ __forceinline__ short f2bf(float f) {
    union { float f; unsigned u; } a; a.f = f;
    unsigned r = a.u + 0x7FFFu + ((a.u >> 16) & 1u);  // RNE
    return (short)(r >> 16);
}
__device__ __forceinline__ float bf2f(short s) {
    union { unsigned u; float f; } a; a.u = ((unsigned)(unsigned short)s) << 16;
    return a.f;
}

// ---------------- K1: fused RMS norm + weight prep (one launch) ------------
// blocks [0,4096): rmsnorm x->xn bf16 (4 rows/block, wave-per-row)
// blocks [4096,5760): Wuv -> Wuv_t bf16, Wo -> Wo_t bf16
__global__ __launch_bounds__(256) void k_pre(
        const float* __restrict__ x, const float* __restrict__ gp,
        short* __restrict__ xn,
        const float* __restrict__ Wuv, const float* __restrict__ Wo,
        short* __restrict__ Wuv_t, short* __restrict__ Wo_t) {
    int bid = blockIdx.x;
    if (bid < 4096) {
        int wave = threadIdx.x >> 6, lane = threadIdx.x & 63;
        long row = (long)bid * 4 + wave;
        float4 xv = ((const float4*)(x + row * DD))[lane];
        float ss = xv.x*xv.x + xv.y*xv.y + xv.z*xv.z + xv.w*xv.w;
        #pragma unroll
        for (int off = 32; off > 0; off >>= 1) ss += __shfl_down(ss, off);
        ss = __shfl(ss, 0);
        float norm = sqrtf(ss) * 0.0625f;              // ||x|| / sqrt(256)
        float scale = gp[0] / fmaxf(norm, 1e-5f);
        short4 o;
        o.x = f2bf(xv.x * scale); o.y = f2bf(xv.y * scale);
        o.z = f2bf(xv.z * scale); o.w = f2bf(xv.w * scale);
        ((short4*)(xn + row * DD))[lane] = o;
    } else {
        int idx = (bid - 4096) * 256 + threadIdx.x;
        if (idx < DD * EE) {
            int d = idx / EE, e = idx % EE;
            Wuv_t[e * DD + d] = f2bf(Wuv[idx]);
        }
        int i2 = idx - DD * EE;
        if (i2 >= 0 && i2 < HH * DD) {
            int h = i2 / DD, d = i2 % DD;
            Wo_t[d * HH + h] = f2bf(Wo[i2]);
        }
    }
}

// ---------------- K3: GEMM1 + silu + split epilogue ------------------------
__global__ __launch_bounds__(256) void k_gemm1(
        const short* __restrict__ xn, const short* __restrict__ Wuv_t,
        const float* __restrict__ b_uv,
        const float* __restrict__ gamma, const float* __restrict__ beta,
        short* __restrict__ u, short* __restrict__ v,
        short* __restrict__ q, short* __restrict__ k) {
    __shared__ short As[64][72];
    __shared__ short Bs[64][72];
    int m0 = blockIdx.x * 64, n0 = blockIdx.y * 64;
    int t = threadIdx.x, w = t >> 6, lane = t & 63;
    int wr = w & 1, wc = w >> 1, l16 = lane & 15, quad = lane >> 4;
    int srow = t >> 3, sch = (t & 7) * 8;
    f32x4 acc[2][2] = {};
    for (int k0 = 0; k0 < DD; k0 += 64) {
        __syncthreads();
        *(bf16x8*)&As[srow][sch]    = *(const bf16x8*)&xn[(long)(m0+srow)*DD + k0 + sch];
        *(bf16x8*)&As[srow+32][sch] = *(const bf16x8*)&xn[(long)(m0+srow+32)*DD + k0 + sch];
        *(bf16x8*)&Bs[srow][sch]    = *(const bf16x8*)&Wuv_t[(long)(n0+srow)*DD + k0 + sch];
        *(bf16x8*)&Bs[srow+32][sch] = *(const bf16x8*)&Wuv_t[(long)(n0+srow+32)*DD + k0 + sch];
        __syncthreads();
        #pragma unroll
        for (int kk = 0; kk < 2; kk++) {
            bf16x8 a0 = *(const bf16x8*)&As[wr*32 +      l16][kk*32 + quad*8];
            bf16x8 a1 = *(const bf16x8*)&As[wr*32 + 16 + l16][kk*32 + quad*8];
            bf16x8 b0 = *(const bf16x8*)&Bs[wc*32 +      l16][kk*32 + quad*8];
            bf16x8 b1 = *(const bf16x8*)&Bs[wc*32 + 16 + l16][kk*32 + quad*8];
            acc[0][0] = __builtin_amdgcn_mfma_f32_16x16x32_bf16(a0, b0, acc[0][0], 0,0,0);
            acc[0][1] = __builtin_amdgcn_mfma_f32_16x16x32_bf16(a0, b1, acc[0][1], 0,0,0);
            acc[1][0] = __builtin_amdgcn_mfma_f32_16x16x32_bf16(a1, b0, acc[1][0], 0,0,0);
            acc[1][1] = __builtin_amdgcn_mfma_f32_16x16x32_bf16(a1, b1, acc[1][1], 0,0,0);
        }
    }
    #pragma unroll
    for (int mt = 0; mt < 2; mt++)
    #pragma unroll
    for (int nt = 0; nt < 2; nt++)
    #pragma unroll
    for (int r = 0; r < 4; r++) {
        int gm = m0 + wr*32 + mt*16 + quad*4 + r;     // C/D: row=(lane>>4)*4+reg
        int ge = n0 + wc*32 + nt*16 + l16;            //      col=lane&15
        float val = acc[mt][nt][r] + b_uv[ge];
        val = val / (1.0f + __expf(-val));            // silu
        if (ge < HH) {
            u[(long)gm*HH + ge] = f2bf(val);
        } else if (ge < 2*HH) {
            v[(long)gm*HH + (ge - HH)] = f2bf(val);
        } else {
            int si = ge - 2*HH;
            q[(long)gm*SS + si] = f2bf(val * gamma[si]      + beta[si]);
            k[(long)gm*SS + si] = f2bf(val * gamma[SS + si] + beta[SS + si]);
        }
    }
}

// ---------------- K4: v -> MFMA B-fragment layout --------------------------
// vfrag[b][mt=m0/32][ht=h/16][lane][e] ; lane=quad*16+l16 holds
// v[b][mt*32 + quad*8 + e][ht*16 + l16].  Each (mt,ht) frag = 1KB contiguous
// so k_attn's PV B-frag loads are single coalesced global_load_dwordx4.
__global__ __launch_bounds__(256) void k_vfrag(
        const short* __restrict__ v, short* __restrict__ vfrag) {
    __shared__ short tile[32][520];   // 32 m-rows x 512 h (+8 pad)
    int mt = blockIdx.x, b = blockIdx.y;
    int t = threadIdx.x;
    const short* vb = v + ((long)b * NN + mt * 32) * HH;
    #pragma unroll
    for (int i = 0; i < 8; i++) {
        int c = t + i * 256, r = c >> 6, co = (c & 63) * 8;
        *(bf16x8*)&tile[r][co] = *(const bf16x8*)&vb[(long)r * HH + co];
    }
    __syncthreads();
    short* dstb = vfrag + (((long)b * 64 + mt) * 32) * 512;
    #pragma unroll
    for (int i = 0; i < 8; i++) {
        int c = t + i * 256, ht = c >> 6, l = c & 63;
        int quad = l >> 4, l16 = l & 15;
        bf16x8 o;
        #pragma unroll
        for (int e = 0; e < 8; e++) o[e] = tile[quad*8 + e][ht*16 + l16];
        *(bf16x8*)&dstb[(long)ht * 512 + l * 8] = o;
    }
}

// ---------------- K5: fused relu^2 attention + u-gate (v4) -----------------
// Block = (batch, 64 q-rows), 8 waves (512 thr), grid 256 = 1 block/CU.
// v3 post-mortem: 140KB LDS/iter + 3 barriers/iter -> 4300cyc/iter (2.5x
// stall over LDS floor). v4: V comes from pre-tiled global fragments
// (coalesced 1KB L2 loads, no LDS, no barrier coupling); ks and Ps double-
// buffered -> ONE barrier/iter. LDS/iter: kf 32KB + af 32KB + P 4KB + k 8KB.
// k pipeline depth 2: preload m0+64 to regs, write m0+32 to ks[p^1].
__global__ __launch_bounds__(512, 2) void k_attn(
        const short* __restrict__ q, const short* __restrict__ k,
        const short* __restrict__ vfrag, const short* __restrict__ u,
        short* __restrict__ gated) {
    __shared__ short ks[2][32][136];  // k-tile: 32 m-rows x 128 s (+8 pad)
    __shared__ short Ps[2][64][40];   // P: 64 q-rows x 32 m (+8 pad)
    int b = blockIdx.x & 7;                  // batch -> XCD pin
    int i0 = (blockIdx.x >> 3) * 64;
    int t = threadIdx.x, w = t >> 6, lane = t & 63;
    int l16 = lane & 15, quad = lane >> 4;
    int qt = w >> 1, mt = w & 1;             // QK tile assignment
    const short* qb  = q + ((long)b * NN + i0) * SS;
    const short* kb  = k + (long)b * NN * SS;
    const short* vfb = vfrag + (long)b * 64 * 32 * 512;
    const float RS = 0.08838834764831845f;   // 1/sqrt(128)

    int krow = t >> 4, kch = (t & 15) * 8;   // k staging map: 32 rows x 256B

    // hoist q B-frags for this wave's q-tile: B[n=q=l16][k=s]
    bf16x8 qf[4];
    #pragma unroll
    for (int kc = 0; kc < 4; kc++)
        qf[kc] = *(const bf16x8*)&qb[(long)(qt*16 + l16)*SS + kc*32 + quad*8];

    // prologue: stage k(m0=0) -> ks[0]; preload k(m0=32) -> kpre
    *(bf16x8*)&ks[0][krow][kch] = *(const bf16x8*)&kb[(long)krow*SS + kch];
    bf16x8 kpre = *(const bf16x8*)&kb[(long)(32 + krow)*SS + kch];
    __syncthreads();

    f32x4 acc[16] = {};
    for (int it = 0; it < NN/32; it++) {
        int p = it & 1;
        int m0 = it * 32;
        // preload k for m0+64 (clamp keeps address valid; value unused at end)
        int mnext = (m0 + 64 < NN) ? m0 + 64 : m0;
        bf16x8 knext = *(const bf16x8*)&kb[(long)(mnext + krow)*SS + kch];
        // this iter's v B-frags: coalesced 1KB global loads (land during QK)
        bf16x8 vf[4];
        #pragma unroll
        for (int jj = 0; jj < 4; jj++)
            vf[jj] = *(const bf16x8*)&vfb[((long)it*32 + (w*4 + jj))*512 + lane*8];
        // QK: S^T tile (16m x 16q), A = k-frags from LDS, B = q-frags in regs
        f32x4 sc = {};
        #pragma unroll
        for (int kc = 0; kc < 4; kc++) {
            bf16x8 kf = *(const bf16x8*)&ks[p][mt*16 + l16][kc*32 + quad*8];
            sc = __builtin_amdgcn_mfma_f32_16x16x32_bf16(kf, qf[kc], sc, 0,0,0);
        }
        short4 pw;
        {
            float s0 = fmaxf(sc[0]*RS, 0.f), s1 = fmaxf(sc[1]*RS, 0.f);
            float s2 = fmaxf(sc[2]*RS, 0.f), s3 = fmaxf(sc[3]*RS, 0.f);
            pw.x = f2bf(s0*s0); pw.y = f2bf(s1*s1);
            pw.z = f2bf(s2*s2); pw.w = f2bf(s3*s3);
        }
        // C-layout: row m = quad*4+r, col q = l16 -> store P[q][m]
        *(short4*)&Ps[p][qt*16 + l16][mt*16 + quad*4] = pw;
        // stage k(m0+32) into the other buffer (loaded last iter, landed)
        *(bf16x8*)&ks[p^1][krow][kch] = kpre;
        kpre = knext;
        __syncthreads();                       // single barrier per iter
        // PV: A-frags from Ps[p] (reused over 4 h-tiles), B = vf in regs
        bf16x8 af[4];
        #pragma unroll
        for (int qq2 = 0; qq2 < 4; qq2++)
            af[qq2] = *(const bf16x8*)&Ps[p][qq2*16 + l16][quad*8];
        #pragma unroll
        for (int jj = 0; jj < 4; jj++)
            #pragma unroll
            for (int qq2 = 0; qq2 < 4; qq2++)
                acc[qq2*4 + jj] = __builtin_amdgcn_mfma_f32_16x16x32_bf16(
                    af[qq2], vf[jj], acc[qq2*4 + jj], 0,0,0);
    }

    // epilogue: u-gate. acc C-layout: row q = quad*4+r, col h = l16
    long rowbase = (long)b * NN + i0;
    #pragma unroll
    for (int qq2 = 0; qq2 < 4; qq2++)
    #pragma unroll
    for (int jj = 0; jj < 4; jj++) {
        int gh = (w*4 + jj)*16 + l16;
        #pragma unroll
        for (int r = 0; r < 4; r++) {
            long grow = rowbase + qq2*16 + quad*4 + r;
            float uval = bf2f(u[grow * HH + gh]);
            gated[grow * HH + gh] = f2bf(acc[qq2*4 + jj][r] * uval);
        }
    }
}

// ---------------- K6: GEMM2 + bias -> fp32 out -----------------------------
__global__ __launch_bounds__(256) void k_gemm2(
        const short* __restrict__ gated, const short* __restrict__ Wo_t,
        const float* __restrict__ b_o, float* __restrict__ out) {
    __shared__ short As[64][72];
    __shared__ short Bs[64][72];
    int m0 = blockIdx.x * 64, n0 = blockIdx.y * 64;
    int t = threadIdx.x, w = t >> 6, lane = t & 63;
    int wr = w & 1, wc = w >> 1, l16 = lane & 15, quad = lane >> 4;
    int srow = t >> 3, sch = (t & 7) * 8;
    f32x4 acc[2][2] = {};
    for (int k0 = 0; k0 < HH; k0 += 64) {
        __syncthreads();
        *(bf16x8*)&As[srow][sch]    = *(const bf16x8*)&gated[(long)(m0+srow)*HH + k0 + sch];
        *(bf16x8*)&As[srow+32][sch] = *(const bf16x8*)&gated[(long)(m0+srow+32)*HH + k0 + sch];
        *(bf16x8*)&Bs[srow][sch]    = *(const bf16x8*)&Wo_t[(long)(n0+srow)*HH + k0 + sch];
        *(bf16x8*)&Bs[srow+32][sch] = *(const bf16x8*)&Wo_t[(long)(n0+srow+32)*HH + k0 + sch];
        __syncthreads();
        #pragma unroll
        for (int kk = 0; kk < 2; kk++) {
            bf16x8 a0 = *(const bf16x8*)&As[wr*32 +      l16][kk*32 + quad*8];
            bf16x8 a1 = *(const bf16x8*)&As[wr*32 + 16 + l16][kk*32 + quad*8];
            bf16x8 b0 = *(const bf16x8*)&Bs[wc*32 +      l16][kk*32 + quad*8];
            bf16x8 b1 = *(const bf16x8*)&Bs[wc*32 + 16 + l16][kk*32 + quad*8];
            acc[0][0] = __builtin_amdgcn_mfma_f32_16x16x32_bf16(a0, b0, acc[0][0], 0,0,0);
            acc[0][1] = __builtin_amdgcn_mfma_f32_16x16x32_bf16(a0, b1, acc[0][1], 0,0,0);
            acc[1][0] = __builtin_amdgcn_mfma_f32_16x16x32_bf16(a1, b0, acc[1][0], 0,0,0);
            acc[1][1] = __builtin_amdgcn_mfma_f32_16x16x32_bf16(a1, b1, acc[1][1], 0,0,0);
        }
    }
    #pragma unroll
    for (int mt = 0; mt < 2; mt++)
    #pragma unroll
    for (int nt = 0; nt < 2; nt++)
    #pragma unroll
    for (int r = 0; r < 4; r++) {
        int gm = m0 + wr*32 + mt*16 + quad*4 + r;
        int gd = n0 + wc*32 + nt*16 + l16;
        out[(long)gm*DD + gd] = acc[mt][nt][r] + b_o[gd];
    }
}

extern "C" void kernel_launch(void* const* d_in, const int* in_sizes, int n_in,
                              void* d_out, int out_size, void* d_ws, size_t ws_size,
                              hipStream_t stream) {
    const float* x     = (const float*)d_in[0];
    const float* g     = (const float*)d_in[1];
    const float* Wuv   = (const float*)d_in[2];
    const float* b_uv  = (const float*)d_in[3];
    const float* gamma = (const float*)d_in[4];
    const float* beta  = (const float*)d_in[5];
    const float* Wo    = (const float*)d_in[6];
    const float* b_o   = (const float*)d_in[7];
    float* out = (float*)d_out;

    short* ws    = (short*)d_ws;
    short* xn    = ws;                                  // 16384*256
    short* Wuv_t = xn    + (long)16384 * 256;           // 1152*256
    short* Wo_t  = Wuv_t + (long)1152 * 256;            // 256*512
    short* u     = Wo_t  + (long)256 * 512;             // 16384*512
    short* v     = u     + (long)16384 * 512;           // 16384*512
    short* vfrag = v     + (long)16384 * 512;           // 16384*512 (frag layout)
    short* qq    = vfrag + (long)16384 * 512;           // 16384*128
    short* kk    = qq    + (long)16384 * 128;           // 16384*128
    short* gated = kk    + (long)16384 * 128;           // 16384*512

    k_pre<<<5760, 256, 0, stream>>>(x, g, xn, Wuv, Wo, Wuv_t, Wo_t);
    k_gemm1<<<dim3(256, 18), 256, 0, stream>>>(xn, Wuv_t, b_uv, gamma, beta, u, v, qq, kk);
    k_vfrag<<<dim3(64, 8), 256, 0, stream>>>(v, vfrag);
    k_attn<<<256, 512, 0, stream>>>(qq, kk, vfrag, u, gated);
    k_gemm2<<<dim3(256, 4), 256, 0, stream>>>(gated, Wo_t, b_o, out);
}